// Round 1
// baseline (339.727 us; speedup 1.0000x reference)
//
#include <hip/hip_runtime.h>
#include <stdint.h>

#define UNITS 64
#define UU 4096          // UNITS*UNITS
#define NG 50
#define NSLOT 51         // 50 gaussians + 1 bias slot
#define GAMMA_C 10.0f
#define STEP_C (30.0f / 49.0f)

__device__ __forceinline__ float bf_lo(uint32_t u) { return __uint_as_float(u << 16); }
__device__ __forceinline__ float bf_hi(uint32_t u) { return __uint_as_float(u & 0xffff0000u); }

// A[g, i*64+j] = sum_k W1[g,k] * W2[k, i*64+j]   (g<50)
// A[50, ij]    = sum_k b1[k]  * W2[k, ij] + b2[ij]
__global__ void k_precompA(const float* __restrict__ W1, const float* __restrict__ b1,
                           const float* __restrict__ W2, const float* __restrict__ b2,
                           float* __restrict__ A) {
  int ij = blockIdx.x * 256 + threadIdx.x;   // 0..4095
  int g = blockIdx.y;                        // 0..50
  float acc = 0.f;
  if (g < NG) {
    const float* w1r = W1 + g * UNITS;
    #pragma unroll 8
    for (int k = 0; k < UNITS; ++k) acc = fmaf(w1r[k], W2[k * UU + ij], acc);
  } else {
    #pragma unroll 8
    for (int k = 0; k < UNITS; ++k) acc = fmaf(b1[k], W2[k * UU + ij], acc);
    acc += b2[ij];
  }
  A[g * UU + ij] = acc;
}

// T5[g, i, m] = sum_j A[g, i*64+j] * Wt[m, j]   -> stored bf16 (RNE)
__global__ void k_precompT5(const float* __restrict__ A, const float* __restrict__ Wt,
                            uint16_t* __restrict__ T5) {
  int idx = blockIdx.x * 256 + threadIdx.x;  // i*64 + m
  int g = blockIdx.y;
  int i = idx >> 6, m = idx & 63;
  const float* ar = A + g * UU + i * UNITS;
  const float* wr = Wt + m * UNITS;
  float acc = 0.f;
  #pragma unroll 8
  for (int j = 0; j < UNITS; ++j) acc = fmaf(ar[j], wr[j], acc);
  uint32_t u = __float_as_uint(acc);
  u += 0x7fffu + ((u >> 16) & 1u);           // round-to-nearest-even to bf16
  T5[g * UU + i * UNITS + m] = (uint16_t)(u >> 16);
}

#define ACC2(u, n0, n1) { a = fmaf(bf_lo(u), (n0), a); a = fmaf(bf_hi(u), (n1), a); }

// One wave per edge. Lane i computes filtered[e, i] and atomically scatters to msg[dst, i].
__global__ void __launch_bounds__(256) k_edge(
    const float* __restrict__ nf, const int* __restrict__ ei,
    const float* __restrict__ dist, const uint16_t* __restrict__ T5,
    float* __restrict__ msg, int E) {
  __shared__ float nfs[4][UNITS];
  int w = threadIdx.x >> 6, lane = threadIdx.x & 63;
  int e = blockIdx.x * 4 + w;
  if (e >= E) return;                        // no block-wide barriers used: safe

  int src = ei[e];
  int dst = ei[E + e];
  float d = dist[e];

  nfs[w][lane] = nf[src * UNITS + lane];     // coalesced gather of the nf row

  // gaussian window: centers lo..lo+5 cover everything above ~2e-15
  int lo = (int)floorf(d * (1.0f / STEP_C)) - 2;
  lo = min(max(lo, 0), NG - 6);
  float df[6];
  #pragma unroll
  for (int l = 0; l < 6; ++l) {
    float t = d - (float)(lo + l) * STEP_C;
    df[l] = __expf(-GAMMA_C * t * t);
  }

  // pull the full nf row into registers (static indexing only)
  float nfr[64];
  #pragma unroll
  for (int q = 0; q < 16; ++q) {
    float4 v = *reinterpret_cast<const float4*>(&nfs[w][q * 4]);
    nfr[4 * q + 0] = v.x; nfr[4 * q + 1] = v.y;
    nfr[4 * q + 2] = v.z; nfr[4 * q + 3] = v.w;
  }

  float accl[7];
  #pragma unroll
  for (int l = 0; l < 7; ++l) {
    int g = (l < 6) ? (lo + l) : NG;         // slot 50 = bias filter, weight 1
    const uint4* row = reinterpret_cast<const uint4*>(T5 + ((g * UNITS + lane) << 6));
    float a = 0.f;
    #pragma unroll
    for (int mb = 0; mb < 8; ++mb) {
      uint4 u = row[mb];                     // 8 bf16 of T5[g, lane, mb*8..+7]
      ACC2(u.x, nfr[mb * 8 + 0], nfr[mb * 8 + 1])
      ACC2(u.y, nfr[mb * 8 + 2], nfr[mb * 8 + 3])
      ACC2(u.z, nfr[mb * 8 + 4], nfr[mb * 8 + 5])
      ACC2(u.w, nfr[mb * 8 + 6], nfr[mb * 8 + 7])
    }
    accl[l] = a;
  }

  float tot = accl[6];
  #pragma unroll
  for (int l = 0; l < 6; ++l) tot = fmaf(df[l], accl[l], tot);

  atomicAdd(&msg[dst * UNITS + lane], tot);
}

// out = softplus(msg) - ln(2), numerically stable
__global__ void k_final(const float* __restrict__ msg, float* __restrict__ out, int n) {
  int i = blockIdx.x * 256 + threadIdx.x;
  if (i >= n) return;
  float x = msg[i];
  float sp = (x > 0.f) ? (x + log1pf(__expf(-x))) : log1pf(__expf(x));
  out[i] = sp - 0.69314718056f;
}

extern "C" void kernel_launch(void* const* d_in, const int* in_sizes, int n_in,
                              void* d_out, int out_size, void* d_ws, size_t ws_size,
                              hipStream_t stream) {
  const float* nf   = (const float*)d_in[0];
  const int*   ei   = (const int*)d_in[1];
  const float* dist = (const float*)d_in[2];
  const float* W1   = (const float*)d_in[3];
  const float* b1   = (const float*)d_in[4];
  const float* W2   = (const float*)d_in[5];
  const float* b2   = (const float*)d_in[6];
  const float* Wt   = (const float*)d_in[7];
  float* out = (float*)d_out;

  int E = in_sizes[2];          // 50000
  int n_out = out_size;         // N_NODES * UNITS = 640000

  // workspace layout
  char* ws = (char*)d_ws;
  float*    A   = (float*)ws;                          // 51*4096*4  = 835584 B
  uint16_t* T5  = (uint16_t*)(ws + 835584);            // 51*4096*2  = 417792 B
  float*    msg = (float*)(ws + 835584 + 417792);      // 640000*4   = 2560000 B

  hipMemsetAsync(msg, 0, (size_t)n_out * sizeof(float), stream);

  k_precompA <<<dim3(16, NSLOT), 256, 0, stream>>>(W1, b1, W2, b2, A);
  k_precompT5<<<dim3(16, NSLOT), 256, 0, stream>>>(A, Wt, T5);
  k_edge     <<<(E + 3) / 4, 256, 0, stream>>>(nf, ei, dist, T5, msg, E);
  k_final    <<<(n_out + 255) / 256, 256, 0, stream>>>(msg, out, n_out);
}